// Round 3
// baseline (10254.221 us; speedup 1.0000x reference)
//
#include <hip/hip_runtime.h>

// ---------------------------------------------------------------------------
// BiGRU encoder, MI355X. Persistent data-flow recurrence (no flags, no fences):
// producers write h via 4B write-through agent atomics; consumers poll the DATA
// with L2-bypassing loads and validate against a bf16-NaN sentinel.
//
// ws layout:
//   Xb    [T][B][F] bf16   33,554,432 B   (x cast to bf16, time-major)
//   Hf    [T][B][F] bf16   33,554,432 B   (forward hidden, sentinel-init)
//   Hb    [T][B][F] bf16   33,554,432 B   (backward hidden, sentinel-init)
//   Wb    [2][2][1536][512] bf16  6,291,456 B  (dir, src{0=Whh,1=Wih})
// ---------------------------------------------------------------------------

#define TT    2048
#define BB    16
#define FF    512
#define LL    10
#define NBLK  32          // blocks per direction
#define NTHR  384         // 6 waves
#define SENT  0x7FFF7FFFu // bf16 NaN pair — real h is always finite/non-NaN

typedef __attribute__((ext_vector_type(8))) short short8;
typedef __attribute__((ext_vector_type(4))) int   int4v;
typedef __attribute__((ext_vector_type(4))) float f32x4;

__device__ __forceinline__ unsigned short f2bf(float f) {
  union { float f; unsigned int u; } v; v.f = f;
  unsigned int u = v.u;
  unsigned int r = (u + 0x7fffu + ((u >> 16) & 1u)) >> 16;
  return (unsigned short)r;
}
__device__ __forceinline__ float bf2f(unsigned short h) {
  union { unsigned int u; float f; } v; v.u = ((unsigned int)h) << 16;
  return v.f;
}

// --- prep: cast x (B,T,N) f32 -> Xb (T,B,F) bf16 ---------------------------
__global__ void prep_x(const float* __restrict__ x, unsigned short* __restrict__ Xb) {
  int i = blockIdx.x * blockDim.x + threadIdx.x;     // over T*B*F = 16,777,216
  int f = i & (FF - 1);
  int b = (i >> 9) & (BB - 1);
  int t = i >> 13;
  Xb[i] = f2bf(x[(size_t)b * (TT * 1025) + t * 1025 + f]);
}

// --- prep: cast weights to bf16, order [Whh_f, Wih_f, Whh_b, Wih_b] --------
__global__ void prep_w(const float* __restrict__ a, const float* __restrict__ b,
                       const float* __restrict__ c, const float* __restrict__ d,
                       unsigned short* __restrict__ Wb) {
  const int M = 1536 * 512;
  int i = blockIdx.x * blockDim.x + threadIdx.x;     // over 4*M = 3,145,728
  int m = i / M, r = i - m * M;
  const float* src = (m == 0) ? a : (m == 1) ? b : (m == 2) ? c : d;
  Wb[i] = f2bf(src[r]);
}

// --- prep: sentinel-fill Hf+Hb (67,108,864 B = 4,194,304 uint4) ------------
__global__ void prep_sent(uint4* __restrict__ H) {
  int i = blockIdx.x * blockDim.x + threadIdx.x;
  H[i] = make_uint4(SENT, SENT, SENT, SENT);
}

// --- persistent recurrent kernel -------------------------------------------
// 64 blocks: blockIdx>>5 = direction, blockIdx&31 = hidden-column slice (16 cols).
// waves 0..2: gh = h@Whh^T (gates r,z,n)  -- poll the h data directly
// waves 3..5: gi = x@Wih^T (gates r,z,n)  -- no recurrence dependency
__global__ void __launch_bounds__(NTHR, 1) bigru_rec(
    const unsigned short* __restrict__ Xb,
    unsigned short* __restrict__ Hf, unsigned short* __restrict__ Hb,
    const unsigned short* __restrict__ Wb,
    const float* __restrict__ bih_f, const float* __restrict__ bhh_f,
    const float* __restrict__ bih_b, const float* __restrict__ bhh_b,
    float* __restrict__ out)
{
  const int bid  = blockIdx.x;
  const int d    = bid >> 5;
  const int j    = bid & 31;
  const int tid  = threadIdx.x;
  const int w    = tid >> 6;
  const int lane = tid & 63;

  unsigned short* Hst = d ? Hb : Hf;
  const float* bih = d ? bih_b : bih_f;
  const float* bhh = d ? bhh_b : bhh_f;

  __shared__ float acc_lds[2][6][16][17];   // double-buffered: 1 barrier/step

  const int g   = (w >= 3) ? (w - 3) : w;  // gate 0=r 1=z 2=n
  const int src = (w >= 3) ? 1 : 0;        // 0=Whh (gh), 1=Wih (gi)
  const int l15 = lane & 15;
  const int lk  = (lane >> 4) * 8;

  // Weight fragments pinned in VGPRs via asm loads (compiler cannot remat).
  int4v wf[16];
  {
    const unsigned short* wrow =
        Wb + (size_t)((d * 2 + src) * 1536 + g * 512 + j * 16 + l15) * 512 + lk;
#pragma unroll
    for (int kk = 0; kk < 16; ++kk)
      asm volatile("global_load_dwordx4 %0, %1, off offset:%2"
                   : "=v"(wf[kk]) : "v"(wrow), "i"(kk * 64));
    asm volatile("s_waitcnt vmcnt(0)" ::: "memory");
    __builtin_amdgcn_sched_barrier(0);
  }

  // elementwise thread mapping (threads 0..255): m = batch row, f = col in slice
  const int m = tid >> 4, f = tid & 15;
  const int col = j * 16 + f;
  float br_i = 0.f, br_h = 0.f, bz_i = 0.f, bz_h = 0.f, bn_i = 0.f, bn_h = 0.f;
  float hcarry = 0.f;                      // fp32 recurrent carry (exact)
  if (tid < 256) {
    br_i = bih[col];        br_h = bhh[col];
    bz_i = bih[512 + col];  bz_h = bhh[512 + col];
    bn_i = bih[1024 + col]; bn_h = bhh[1024 + col];
  }
  __syncthreads();

  for (int t = 0; t < TT; ++t) {
    const int tx = d ? (TT - 1 - t) : t;

    // early-issue residual x load (used after the barrier)
    float xv = 0.f;
    if (tid < 256) xv = bf2f(Xb[(size_t)(tx * BB + m) * FF + col]);

    f32x4 acc0 = {0.f, 0.f, 0.f, 0.f}, acc1 = {0.f, 0.f, 0.f, 0.f};
    int4v af[16];
    bool have = false;

    if (src == 1) {
      const unsigned short* Arow = Xb + (size_t)(tx * BB + l15) * FF + lk;
#pragma unroll
      for (int kk = 0; kk < 16; ++kk)
        af[kk] = *(const int4v*)(Arow + kk * 32);
      have = true;
    } else if (t > 0) {
      // Poll the h_{t-1} data itself: L2-bypassing loads, sentinel-validate.
      const unsigned short* Arow = Hst + (size_t)((t - 1) * BB + l15) * FF + lk;
      while (true) {
#pragma unroll
        for (int kk = 0; kk < 16; ++kk)
          asm volatile("global_load_dwordx4 %0, %1, off offset:%2 sc0 sc1"
                       : "=v"(af[kk]) : "v"(Arow), "i"(kk * 64));
        asm volatile("s_waitcnt vmcnt(0)" ::: "memory");
        __builtin_amdgcn_sched_barrier(0);
        int bad = 0;
#pragma unroll
        for (int kk = 0; kk < 16; ++kk) {
          bad |= (af[kk].x == (int)SENT);
          bad |= (af[kk].y == (int)SENT);
          bad |= (af[kk].z == (int)SENT);
          bad |= (af[kk].w == (int)SENT);
        }
        if (__all(bad == 0)) break;
      }
      __builtin_amdgcn_sched_barrier(0);
      have = true;
    }

    if (have) {
#pragma unroll
      for (int kk = 0; kk < 16; kk += 2) {
        acc0 = __builtin_amdgcn_mfma_f32_16x16x32_bf16(
            __builtin_bit_cast(short8, af[kk]),     __builtin_bit_cast(short8, wf[kk]),     acc0, 0, 0, 0);
        acc1 = __builtin_amdgcn_mfma_f32_16x16x32_bf16(
            __builtin_bit_cast(short8, af[kk + 1]), __builtin_bit_cast(short8, wf[kk + 1]), acc1, 0, 0, 0);
      }
    }
    // D layout (verified m89): col = lane&15, row = (lane>>4)*4 + reg
#pragma unroll
    for (int jj = 0; jj < 4; ++jj)
      acc_lds[t & 1][w][(lane >> 4) * 4 + jj][l15] = acc0[jj] + acc1[jj];
    __syncthreads();                       // the ONLY barrier per step

    if (tid < 256) {
      const float ghr = acc_lds[t & 1][0][m][f] + br_h;
      const float ghz = acc_lds[t & 1][1][m][f] + bz_h;
      const float ghn = acc_lds[t & 1][2][m][f] + bn_h;
      const float gir = acc_lds[t & 1][3][m][f] + br_i;
      const float giz = acc_lds[t & 1][4][m][f] + bz_i;
      const float gin = acc_lds[t & 1][5][m][f] + bn_i;
      const float r = 1.f / (1.f + __expf(-(gir + ghr)));
      const float z = 1.f / (1.f + __expf(-(giz + ghz)));
      const float e = __expf(2.f * (gin + r * ghn));
      const float n = 1.f - 2.f / (e + 1.f);          // tanh, inf-safe
      const float h2 = (1.f - z) * n + z * hcarry + xv;
      hcarry = h2;
      // publish h: paired 4B write-through agent atomics — and move on.
      const unsigned short us = f2bf(h2);
      const unsigned int other =
          (unsigned int)(unsigned short)__shfl_xor((int)us, 1);
      if ((f & 1) == 0) {
        const unsigned int word = (unsigned int)us | (other << 16);
        unsigned int* wp = (unsigned int*)(Hst + (size_t)(t * BB + m) * FF + col);
        __hip_atomic_store(wp, word, __ATOMIC_RELAXED, __HIP_MEMORY_SCOPE_AGENT);
      }
      // out store off the critical path
      if (t >= LL && t < TT - LL)
        out[((size_t)m * (TT - 2 * LL) + (t - LL)) * 1024 + d * 512 + col] = h2;
    }
  }
}

// ---------------------------------------------------------------------------
extern "C" void kernel_launch(void* const* d_in, const int* in_sizes, int n_in,
                              void* d_out, int out_size, void* d_ws, size_t ws_size,
                              hipStream_t stream) {
  const float* x     = (const float*)d_in[0];
  const float* Wih_f = (const float*)d_in[1];
  const float* Whh_f = (const float*)d_in[2];
  const float* bih_f = (const float*)d_in[3];
  const float* bhh_f = (const float*)d_in[4];
  const float* Wih_b = (const float*)d_in[5];
  const float* Whh_b = (const float*)d_in[6];
  const float* bih_b = (const float*)d_in[7];
  const float* bhh_b = (const float*)d_in[8];
  float* out = (float*)d_out;

  char* ws = (char*)d_ws;
  unsigned short* Xb = (unsigned short*)ws;
  unsigned short* Hf = (unsigned short*)(ws + (size_t)33554432);
  unsigned short* Hb = (unsigned short*)(ws + (size_t)2 * 33554432);
  unsigned short* Wb = (unsigned short*)(ws + (size_t)3 * 33554432);

  prep_x<<<65536, 256, 0, stream>>>(x, Xb);
  prep_w<<<12288, 256, 0, stream>>>(Whh_f, Wih_f, Whh_b, Wih_b, Wb);
  prep_sent<<<16384, 256, 0, stream>>>((uint4*)Hf);   // fills Hf AND Hb (contiguous)
  bigru_rec<<<64, NTHR, 0, stream>>>(Xb, Hf, Hb, Wb, bih_f, bhh_f, bih_b, bhh_b,
                                     out);
}

// Round 5
// 9428.359 us; speedup vs baseline: 1.0876x; 1.0876x over previous
//
#include <hip/hip_runtime.h>

// ---------------------------------------------------------------------------
// BiGRU encoder, MI355X. Round 5: round-2's PROVEN sync protocol + round-4's
// structure (in-register elementwise, wave-B gi FIFO, no per-step barrier).
// No inline-asm loads anywhere (r4's NaN suspect). No XCD-local mode.
//
// 64 blocks (grid=64), 128 threads (2 waves), 1 block/CU.
//   wave A: gh = h@Whh^T (48 MFMA) + gates + h publish, all in-register.
//   wave B: gi = x@Wih^T + bih + residual x -> LDS FIFO (runs ahead, RD=4).
//
// ws layout:
//   Xb   [T][B][F] bf16      33,554,432 B
//   Hf   [T][B][F] bf16      33,554,432 B
//   Hb   [T][B][F] bf16      33,554,432 B
//   Wb   [2][2][1536][512]    6,291,456 B   (dir, src{0=Whh,1=Wih})
//   flags 2*32 int
// ---------------------------------------------------------------------------

#define TT 2048
#define BB 16
#define FF 512
#define LL 10
#define RD 4
#define NTHR 128

typedef __attribute__((ext_vector_type(8))) short short8;
typedef __attribute__((ext_vector_type(4))) int   int4v;
typedef __attribute__((ext_vector_type(4))) float f32x4;

__device__ __forceinline__ unsigned short f2bf(float f) {
  union { float f; unsigned int u; } v; v.f = f;
  unsigned int u = v.u;
  return (unsigned short)((u + 0x7fffu + ((u >> 16) & 1u)) >> 16);
}
__device__ __forceinline__ float bf2f(unsigned short h) {
  union { unsigned int u; float f; } v; v.u = ((unsigned int)h) << 16;
  return v.f;
}

__global__ void prep_x(const float* __restrict__ x, unsigned short* __restrict__ Xb) {
  int i = blockIdx.x * blockDim.x + threadIdx.x;
  int f = i & (FF - 1);
  int b = (i >> 9) & (BB - 1);
  int t = i >> 13;
  Xb[i] = f2bf(x[(size_t)b * (TT * 1025) + t * 1025 + f]);
}

__global__ void prep_w(const float* __restrict__ a, const float* __restrict__ b,
                       const float* __restrict__ c, const float* __restrict__ d,
                       unsigned short* __restrict__ Wb) {
  const int M = 1536 * 512;
  int i = blockIdx.x * blockDim.x + threadIdx.x;
  int m = i / M, r = i - m * M;
  const float* src = (m == 0) ? a : (m == 1) ? b : (m == 2) ? c : d;
  Wb[i] = f2bf(src[r]);
}

__global__ void prep_flags(int* __restrict__ flags) {
  int i = threadIdx.x;
  if (i < 64) flags[i] = 0;
}

// ---------------------------------------------------------------------------
__global__ void __launch_bounds__(NTHR, 1) bigru_rec(
    const unsigned short* __restrict__ Xb,
    unsigned short* __restrict__ Hf, unsigned short* __restrict__ Hb,
    const unsigned short* __restrict__ Wb,
    const float* __restrict__ bih_f, const float* __restrict__ bhh_f,
    const float* __restrict__ bih_b, const float* __restrict__ bhh_b,
    int* __restrict__ flags, float* __restrict__ out)
{
  const int bid  = blockIdx.x;
  const int d    = bid >> 5;           // direction
  const int j    = bid & 31;           // slice (16 hidden cols)
  const int tid  = threadIdx.x;
  const int w    = tid >> 6;           // 0 = gh wave, 1 = gi wave
  const int lane = tid & 63;
  const int l15  = lane & 15;
  const int hi   = lane >> 4;
  const int lk   = hi * 8;
  const int col  = j * 16 + l15;

  unsigned short* Hst = d ? Hb : Hf;
  int* flg = flags + d * 32;
  const float* bih = d ? bih_b : bih_f;
  const float* bhh = d ? bhh_b : bhh_f;

  __shared__ float fifo[RD][64][17];   // [slot][lane][{gir4,giz4,gin4,xv4},pad]
  __shared__ int wrote_s, consumed_s;
  if (tid == 0) { wrote_s = 0; consumed_s = 0; }
  __syncthreads();

  // Weights: plain loads (compiler-managed waits), then pin via opaque asm def
  // (prevents remat; safe spills if the allocator must).
  const int src = w;                   // 0=Whh, 1=Wih
  int4v wf[3][16];
#pragma unroll
  for (int g = 0; g < 3; ++g) {
    const unsigned short* wrow =
        Wb + (size_t)((d * 2 + src) * 1536 + g * 512 + j * 16 + l15) * 512 + lk;
#pragma unroll
    for (int kk = 0; kk < 16; ++kk)
      wf[g][kk] = *(const int4v*)(wrow + kk * 32);
  }
#pragma unroll
  for (int g = 0; g < 3; ++g)
#pragma unroll
    for (int kk = 0; kk < 16; ++kk)
      asm volatile("" : "+v"(wf[g][kk]));

  if (w == 0) {
    // ====================== WAVE A: gh + gates + publish ===================
    const float bh0 = bhh[col], bh1 = bhh[512 + col], bh2 = bhh[1024 + col];
    float hc[4] = {0.f, 0.f, 0.f, 0.f};   // fp32 carry, rows hi*4+jj

    for (int t = 0; t < TT; ++t) {
      f32x4 a0 = {0,0,0,0}, a1 = {0,0,0,0}, a2 = {0,0,0,0},
            a3 = {0,0,0,0}, a4 = {0,0,0,0}, a5 = {0,0,0,0};
      if (t > 0) {
        int vv = t;
        do {
          if (lane < 32)
            vv = __hip_atomic_load(flg + lane, __ATOMIC_RELAXED,
                                   __HIP_MEMORY_SCOPE_AGENT);
        } while (!__all(lane < 32 ? (vv >= t) : 1));
        __builtin_amdgcn_sched_barrier(0);   // no load hoisting above the poll
        const unsigned short* Arow =
            Hst + (size_t)((t - 1) * BB + l15) * FF + lk;
        int4v af[16];
#pragma unroll
        for (int kk = 0; kk < 16; ++kk)
          af[kk] = *(const int4v*)(Arow + kk * 32);
#pragma unroll
        for (int kk = 0; kk < 16; kk += 2) {
          a0 = __builtin_amdgcn_mfma_f32_16x16x32_bf16(__builtin_bit_cast(short8, af[kk]),     __builtin_bit_cast(short8, wf[0][kk]),     a0, 0, 0, 0);
          a2 = __builtin_amdgcn_mfma_f32_16x16x32_bf16(__builtin_bit_cast(short8, af[kk]),     __builtin_bit_cast(short8, wf[1][kk]),     a2, 0, 0, 0);
          a4 = __builtin_amdgcn_mfma_f32_16x16x32_bf16(__builtin_bit_cast(short8, af[kk]),     __builtin_bit_cast(short8, wf[2][kk]),     a4, 0, 0, 0);
          a1 = __builtin_amdgcn_mfma_f32_16x16x32_bf16(__builtin_bit_cast(short8, af[kk + 1]), __builtin_bit_cast(short8, wf[0][kk + 1]), a1, 0, 0, 0);
          a3 = __builtin_amdgcn_mfma_f32_16x16x32_bf16(__builtin_bit_cast(short8, af[kk + 1]), __builtin_bit_cast(short8, wf[1][kk + 1]), a3, 0, 0, 0);
          a5 = __builtin_amdgcn_mfma_f32_16x16x32_bf16(__builtin_bit_cast(short8, af[kk + 1]), __builtin_bit_cast(short8, wf[2][kk + 1]), a5, 0, 0, 0);
        }
      }
      // gi + residual from wave B (runs ahead; normally no wait)
      const int slot = t & (RD - 1);
      while (__hip_atomic_load(&wrote_s, __ATOMIC_ACQUIRE,
                               __HIP_MEMORY_SCOPE_WORKGROUP) < t + 1) {}
      float fr[4], fz[4], fn[4], fx[4];
#pragma unroll
      for (int jj = 0; jj < 4; ++jj) {
        fr[jj] = fifo[slot][lane][jj];
        fz[jj] = fifo[slot][lane][4 + jj];
        fn[jj] = fifo[slot][lane][8 + jj];
        fx[jj] = fifo[slot][lane][12 + jj];
      }
      __hip_atomic_store(&consumed_s, t + 1, __ATOMIC_RELEASE,
                         __HIP_MEMORY_SCOPE_WORKGROUP);

      unsigned short us[4]; float h2v[4];
#pragma unroll
      for (int jj = 0; jj < 4; ++jj) {
        const float ghr = a0[jj] + a1[jj] + bh0;
        const float ghz = a2[jj] + a3[jj] + bh1;
        const float ghn = a4[jj] + a5[jj] + bh2;
        const float rr = 1.f / (1.f + __expf(-(fr[jj] + ghr)));
        const float zz = 1.f / (1.f + __expf(-(fz[jj] + ghz)));
        const float ee = __expf(2.f * (fn[jj] + rr * ghn));
        const float nn = 1.f - 2.f / (ee + 1.f);        // tanh, inf-safe
        const float h2 = (1.f - zz) * nn + zz * hc[jj] + fx[jj];
        hc[jj] = h2; h2v[jj] = h2; us[jj] = f2bf(h2);
      }
      // publish h: paired 4B write-through agent-relaxed stores (r2-proven)
#pragma unroll
      for (int jj = 0; jj < 4; ++jj) {
        const unsigned int other =
            (unsigned int)(unsigned short)__shfl_xor((int)us[jj], 1);
        if (!(lane & 1)) {
          const unsigned int word = (unsigned int)us[jj] | (other << 16);
          unsigned int* wp = (unsigned int*)
              (Hst + (size_t)(t * BB + hi * 4 + jj) * FF + col);
          __hip_atomic_store(wp, word, __ATOMIC_RELAXED,
                             __HIP_MEMORY_SCOPE_AGENT);
        }
      }
      asm volatile("s_waitcnt vmcnt(0)" ::: "memory");   // h at coherence point
      if (lane == 0)
        __hip_atomic_store(flg + j, t + 1, __ATOMIC_RELAXED,
                           __HIP_MEMORY_SCOPE_AGENT);
      // out store off the critical path
      if (t >= LL && t < TT - LL) {
#pragma unroll
        for (int jj = 0; jj < 4; ++jj)
          out[((size_t)(hi * 4 + jj) * (TT - 2 * LL) + (t - LL)) * 1024
              + d * 512 + col] = h2v[jj];
      }
    }
  } else {
    // ====================== WAVE B: gi + residual -> FIFO ==================
    const float bi0 = bih[col], bi1 = bih[512 + col], bi2 = bih[1024 + col];
    for (int t = 0; t < TT; ++t) {
      const int slot = t & (RD - 1);
      while (t - __hip_atomic_load(&consumed_s, __ATOMIC_ACQUIRE,
                                   __HIP_MEMORY_SCOPE_WORKGROUP) >= RD) {}
      const int tx = d ? (TT - 1 - t) : t;
      const unsigned short* Arow = Xb + (size_t)(tx * BB + l15) * FF + lk;
      int4v af[16];
#pragma unroll
      for (int kk = 0; kk < 16; ++kk)
        af[kk] = *(const int4v*)(Arow + kk * 32);
      f32x4 a0 = {0,0,0,0}, a1 = {0,0,0,0}, a2 = {0,0,0,0},
            a3 = {0,0,0,0}, a4 = {0,0,0,0}, a5 = {0,0,0,0};
#pragma unroll
      for (int kk = 0; kk < 16; kk += 2) {
        a0 = __builtin_amdgcn_mfma_f32_16x16x32_bf16(__builtin_bit_cast(short8, af[kk]),     __builtin_bit_cast(short8, wf[0][kk]),     a0, 0, 0, 0);
        a2 = __builtin_amdgcn_mfma_f32_16x16x32_bf16(__builtin_bit_cast(short8, af[kk]),     __builtin_bit_cast(short8, wf[1][kk]),     a2, 0, 0, 0);
        a4 = __builtin_amdgcn_mfma_f32_16x16x32_bf16(__builtin_bit_cast(short8, af[kk]),     __builtin_bit_cast(short8, wf[2][kk]),     a4, 0, 0, 0);
        a1 = __builtin_amdgcn_mfma_f32_16x16x32_bf16(__builtin_bit_cast(short8, af[kk + 1]), __builtin_bit_cast(short8, wf[0][kk + 1]), a1, 0, 0, 0);
        a3 = __builtin_amdgcn_mfma_f32_16x16x32_bf16(__builtin_bit_cast(short8, af[kk + 1]), __builtin_bit_cast(short8, wf[1][kk + 1]), a3, 0, 0, 0);
        a5 = __builtin_amdgcn_mfma_f32_16x16x32_bf16(__builtin_bit_cast(short8, af[kk + 1]), __builtin_bit_cast(short8, wf[2][kk + 1]), a5, 0, 0, 0);
      }
      float xv[4];
#pragma unroll
      for (int jj = 0; jj < 4; ++jj)
        xv[jj] = bf2f(Xb[(size_t)(tx * BB + hi * 4 + jj) * FF + col]);
#pragma unroll
      for (int jj = 0; jj < 4; ++jj) {
        fifo[slot][lane][jj]      = a0[jj] + a1[jj] + bi0;
        fifo[slot][lane][4 + jj]  = a2[jj] + a3[jj] + bi1;
        fifo[slot][lane][8 + jj]  = a4[jj] + a5[jj] + bi2;
        fifo[slot][lane][12 + jj] = xv[jj];
      }
      __hip_atomic_store(&wrote_s, t + 1, __ATOMIC_RELEASE,
                         __HIP_MEMORY_SCOPE_WORKGROUP);
    }
  }
}

// ---------------------------------------------------------------------------
extern "C" void kernel_launch(void* const* d_in, const int* in_sizes, int n_in,
                              void* d_out, int out_size, void* d_ws, size_t ws_size,
                              hipStream_t stream) {
  const float* x     = (const float*)d_in[0];
  const float* Wih_f = (const float*)d_in[1];
  const float* Whh_f = (const float*)d_in[2];
  const float* bih_f = (const float*)d_in[3];
  const float* bhh_f = (const float*)d_in[4];
  const float* Wih_b = (const float*)d_in[5];
  const float* Whh_b = (const float*)d_in[6];
  const float* bih_b = (const float*)d_in[7];
  const float* bhh_b = (const float*)d_in[8];
  float* out = (float*)d_out;

  char* ws = (char*)d_ws;
  unsigned short* Xb = (unsigned short*)ws;
  unsigned short* Hf = (unsigned short*)(ws + (size_t)33554432);
  unsigned short* Hb = (unsigned short*)(ws + (size_t)2 * 33554432);
  unsigned short* Wb = (unsigned short*)(ws + (size_t)3 * 33554432);
  int* flags         = (int*)(ws + (size_t)3 * 33554432 + 6291456);

  prep_x<<<65536, 256, 0, stream>>>(x, Xb);
  prep_w<<<12288, 256, 0, stream>>>(Whh_f, Wih_f, Whh_b, Wih_b, Wb);
  prep_flags<<<1, 64, 0, stream>>>(flags);
  bigru_rec<<<64, NTHR, 0, stream>>>(Xb, Hf, Hb, Wb, bih_f, bhh_f, bih_b, bhh_b,
                                     flags, out);
}

// Round 6
// 5941.691 us; speedup vs baseline: 1.7258x; 1.5868x over previous
//
#include <hip/hip_runtime.h>

// ---------------------------------------------------------------------------
// BiGRU encoder, MI355X. Round 6 = round 5 structure (proven correct) with
// weights homed in AGPRs via inline-asm MFMA ("a" B-operand constraint):
// kills the r5 VGPR spill-reload (~2500 cy/step). Wave A runs at setprio(1).
//
// 64 blocks, 128 threads (2 waves), 1 block/CU.
//   wave A: gh = h@Whh^T (48 MFMA, B from AGPR) + gates + publish, in-register.
//   wave B: gi = x@Wih^T + bih + residual x -> LDS FIFO (runs ahead, RD=4).
//
// ws layout:
//   Xb   [T][B][F] bf16      33,554,432 B
//   Hf   [T][B][F] bf16      33,554,432 B
//   Hb   [T][B][F] bf16      33,554,432 B
//   Wb   [2][2][1536][512]    6,291,456 B   (dir, src{0=Whh,1=Wih})
//   flags 2*32 int
// ---------------------------------------------------------------------------

#define TT 2048
#define BB 16
#define FF 512
#define LL 10
#define RD 4
#define NTHR 128

typedef __attribute__((ext_vector_type(8))) short short8;
typedef __attribute__((ext_vector_type(4))) int   int4v;
typedef __attribute__((ext_vector_type(4))) float f32x4;

// D = A*B + C, B operand pinned to AGPR (weights live there loop-invariantly).
#define MFMA_AB(acc, a, b) \
  asm("v_mfma_f32_16x16x32_bf16 %0, %1, %2, %0" : "+v"(acc) : "v"(a), "a"(b))

__device__ __forceinline__ unsigned short f2bf(float f) {
  union { float f; unsigned int u; } v; v.f = f;
  unsigned int u = v.u;
  return (unsigned short)((u + 0x7fffu + ((u >> 16) & 1u)) >> 16);
}
__device__ __forceinline__ float bf2f(unsigned short h) {
  union { unsigned int u; float f; } v; v.u = ((unsigned int)h) << 16;
  return v.f;
}

__global__ void prep_x(const float* __restrict__ x, unsigned short* __restrict__ Xb) {
  int i = blockIdx.x * blockDim.x + threadIdx.x;
  int f = i & (FF - 1);
  int b = (i >> 9) & (BB - 1);
  int t = i >> 13;
  Xb[i] = f2bf(x[(size_t)b * (TT * 1025) + t * 1025 + f]);
}

__global__ void prep_w(const float* __restrict__ a, const float* __restrict__ b,
                       const float* __restrict__ c, const float* __restrict__ d,
                       unsigned short* __restrict__ Wb) {
  const int M = 1536 * 512;
  int i = blockIdx.x * blockDim.x + threadIdx.x;
  int m = i / M, r = i - m * M;
  const float* src = (m == 0) ? a : (m == 1) ? b : (m == 2) ? c : d;
  Wb[i] = f2bf(src[r]);
}

__global__ void prep_flags(int* __restrict__ flags) {
  int i = threadIdx.x;
  if (i < 64) flags[i] = 0;
}

// ---------------------------------------------------------------------------
__global__ void __launch_bounds__(NTHR, 1) bigru_rec(
    const unsigned short* __restrict__ Xb,
    unsigned short* __restrict__ Hf, unsigned short* __restrict__ Hb,
    const unsigned short* __restrict__ Wb,
    const float* __restrict__ bih_f, const float* __restrict__ bhh_f,
    const float* __restrict__ bih_b, const float* __restrict__ bhh_b,
    int* __restrict__ flags, float* __restrict__ out)
{
  const int bid  = blockIdx.x;
  const int d    = bid >> 5;           // direction
  const int j    = bid & 31;           // slice (16 hidden cols)
  const int tid  = threadIdx.x;
  const int w    = tid >> 6;           // 0 = gh wave, 1 = gi wave
  const int lane = tid & 63;
  const int l15  = lane & 15;
  const int hi   = lane >> 4;
  const int lk   = hi * 8;
  const int col  = j * 16 + l15;

  unsigned short* Hst = d ? Hb : Hf;
  int* flg = flags + d * 32;
  const float* bih = d ? bih_b : bih_f;
  const float* bhh = d ? bhh_b : bhh_f;

  __shared__ float fifo[RD][64][17];   // [slot][lane][{gir4,giz4,gin4,xv4},pad]
  __shared__ int wrote_s, consumed_s;
  if (tid == 0) { wrote_s = 0; consumed_s = 0; }
  __syncthreads();

  // Weights: plain loads (compiler-managed waits). Used ONLY via the "a"
  // MFMA constraint -> allocator homes them in AGPRs (192 regs, no spill).
  const int src = w;                   // 0=Whh, 1=Wih
  int4v wf[3][16];
#pragma unroll
  for (int g = 0; g < 3; ++g) {
    const unsigned short* wrow =
        Wb + (size_t)((d * 2 + src) * 1536 + g * 512 + j * 16 + l15) * 512 + lk;
#pragma unroll
    for (int kk = 0; kk < 16; ++kk)
      wf[g][kk] = *(const int4v*)(wrow + kk * 32);
  }

  if (w == 0) {
    // ====================== WAVE A: gh + gates + publish ===================
    __builtin_amdgcn_s_setprio(1);     // favor the critical wave on this CU
    const float bh0 = bhh[col], bh1 = bhh[512 + col], bh2 = bhh[1024 + col];
    float hc[4] = {0.f, 0.f, 0.f, 0.f};   // fp32 carry, rows hi*4+jj

    for (int t = 0; t < TT; ++t) {
      f32x4 a0 = {0,0,0,0}, a1 = {0,0,0,0}, a2 = {0,0,0,0},
            a3 = {0,0,0,0}, a4 = {0,0,0,0}, a5 = {0,0,0,0};
      if (t > 0) {
        int vv = t;
        do {
          if (lane < 32)
            vv = __hip_atomic_load(flg + lane, __ATOMIC_RELAXED,
                                   __HIP_MEMORY_SCOPE_AGENT);
        } while (!__all(lane < 32 ? (vv >= t) : 1));
        __builtin_amdgcn_sched_barrier(0);   // no load hoisting above the poll
        const unsigned short* Arow =
            Hst + (size_t)((t - 1) * BB + l15) * FF + lk;
        int4v af[16];
#pragma unroll
        for (int kk = 0; kk < 16; ++kk)
          af[kk] = *(const int4v*)(Arow + kk * 32);
#pragma unroll
        for (int kk = 0; kk < 16; kk += 2) {
          MFMA_AB(a0, af[kk],     wf[0][kk]);
          MFMA_AB(a2, af[kk],     wf[1][kk]);
          MFMA_AB(a4, af[kk],     wf[2][kk]);
          MFMA_AB(a1, af[kk + 1], wf[0][kk + 1]);
          MFMA_AB(a3, af[kk + 1], wf[1][kk + 1]);
          MFMA_AB(a5, af[kk + 1], wf[2][kk + 1]);
        }
        asm volatile("s_nop 7\n\ts_nop 7");  // MFMA D -> VALU read hazard guard
      }
      // gi + residual from wave B (runs ahead; normally no wait)
      const int slot = t & (RD - 1);
      while (__hip_atomic_load(&wrote_s, __ATOMIC_ACQUIRE,
                               __HIP_MEMORY_SCOPE_WORKGROUP) < t + 1) {}
      float fr[4], fz[4], fn[4], fx[4];
#pragma unroll
      for (int jj = 0; jj < 4; ++jj) {
        fr[jj] = fifo[slot][lane][jj];
        fz[jj] = fifo[slot][lane][4 + jj];
        fn[jj] = fifo[slot][lane][8 + jj];
        fx[jj] = fifo[slot][lane][12 + jj];
      }
      __hip_atomic_store(&consumed_s, t + 1, __ATOMIC_RELEASE,
                         __HIP_MEMORY_SCOPE_WORKGROUP);

      unsigned short us[4]; float h2v[4];
#pragma unroll
      for (int jj = 0; jj < 4; ++jj) {
        const float ghr = a0[jj] + a1[jj] + bh0;
        const float ghz = a2[jj] + a3[jj] + bh1;
        const float ghn = a4[jj] + a5[jj] + bh2;
        const float rr = 1.f / (1.f + __expf(-(fr[jj] + ghr)));
        const float zz = 1.f / (1.f + __expf(-(fz[jj] + ghz)));
        const float ee = __expf(2.f * (fn[jj] + rr * ghn));
        const float nn = 1.f - 2.f / (ee + 1.f);        // tanh, inf-safe
        const float h2 = (1.f - zz) * nn + zz * hc[jj] + fx[jj];
        hc[jj] = h2; h2v[jj] = h2; us[jj] = f2bf(h2);
      }
      // publish h: paired 4B write-through agent-relaxed stores (r2-proven)
#pragma unroll
      for (int jj = 0; jj < 4; ++jj) {
        const unsigned int other =
            (unsigned int)(unsigned short)__shfl_xor((int)us[jj], 1);
        if (!(lane & 1)) {
          const unsigned int word = (unsigned int)us[jj] | (other << 16);
          unsigned int* wp = (unsigned int*)
              (Hst + (size_t)(t * BB + hi * 4 + jj) * FF + col);
          __hip_atomic_store(wp, word, __ATOMIC_RELAXED,
                             __HIP_MEMORY_SCOPE_AGENT);
        }
      }
      asm volatile("s_waitcnt vmcnt(0)" ::: "memory");   // h at coherence point
      if (lane == 0)
        __hip_atomic_store(flg + j, t + 1, __ATOMIC_RELAXED,
                           __HIP_MEMORY_SCOPE_AGENT);
      // out store off the critical path
      if (t >= LL && t < TT - LL) {
#pragma unroll
        for (int jj = 0; jj < 4; ++jj)
          out[((size_t)(hi * 4 + jj) * (TT - 2 * LL) + (t - LL)) * 1024
              + d * 512 + col] = h2v[jj];
      }
    }
  } else {
    // ====================== WAVE B: gi + residual -> FIFO ==================
    const float bi0 = bih[col], bi1 = bih[512 + col], bi2 = bih[1024 + col];
    for (int t = 0; t < TT; ++t) {
      const int slot = t & (RD - 1);
      while (t - __hip_atomic_load(&consumed_s, __ATOMIC_ACQUIRE,
                                   __HIP_MEMORY_SCOPE_WORKGROUP) >= RD) {}
      const int tx = d ? (TT - 1 - t) : t;
      const unsigned short* Arow = Xb + (size_t)(tx * BB + l15) * FF + lk;
      int4v af[16];
#pragma unroll
      for (int kk = 0; kk < 16; ++kk)
        af[kk] = *(const int4v*)(Arow + kk * 32);
      f32x4 a0 = {0,0,0,0}, a1 = {0,0,0,0}, a2 = {0,0,0,0},
            a3 = {0,0,0,0}, a4 = {0,0,0,0}, a5 = {0,0,0,0};
#pragma unroll
      for (int kk = 0; kk < 16; kk += 2) {
        MFMA_AB(a0, af[kk],     wf[0][kk]);
        MFMA_AB(a2, af[kk],     wf[1][kk]);
        MFMA_AB(a4, af[kk],     wf[2][kk]);
        MFMA_AB(a1, af[kk + 1], wf[0][kk + 1]);
        MFMA_AB(a3, af[kk + 1], wf[1][kk + 1]);
        MFMA_AB(a5, af[kk + 1], wf[2][kk + 1]);
      }
      asm volatile("s_nop 7\n\ts_nop 7");    // MFMA D -> VALU read hazard guard
      float xv[4];
#pragma unroll
      for (int jj = 0; jj < 4; ++jj)
        xv[jj] = bf2f(Xb[(size_t)(tx * BB + hi * 4 + jj) * FF + col]);
#pragma unroll
      for (int jj = 0; jj < 4; ++jj) {
        fifo[slot][lane][jj]      = a0[jj] + a1[jj] + bi0;
        fifo[slot][lane][4 + jj]  = a2[jj] + a3[jj] + bi1;
        fifo[slot][lane][8 + jj]  = a4[jj] + a5[jj] + bi2;
        fifo[slot][lane][12 + jj] = xv[jj];
      }
      __hip_atomic_store(&wrote_s, t + 1, __ATOMIC_RELEASE,
                         __HIP_MEMORY_SCOPE_WORKGROUP);
    }
  }
}

// ---------------------------------------------------------------------------
extern "C" void kernel_launch(void* const* d_in, const int* in_sizes, int n_in,
                              void* d_out, int out_size, void* d_ws, size_t ws_size,
                              hipStream_t stream) {
  const float* x     = (const float*)d_in[0];
  const float* Wih_f = (const float*)d_in[1];
  const float* Whh_f = (const float*)d_in[2];
  const float* bih_f = (const float*)d_in[3];
  const float* bhh_f = (const float*)d_in[4];
  const float* Wih_b = (const float*)d_in[5];
  const float* Whh_b = (const float*)d_in[6];
  const float* bih_b = (const float*)d_in[7];
  const float* bhh_b = (const float*)d_in[8];
  float* out = (float*)d_out;

  char* ws = (char*)d_ws;
  unsigned short* Xb = (unsigned short*)ws;
  unsigned short* Hf = (unsigned short*)(ws + (size_t)33554432);
  unsigned short* Hb = (unsigned short*)(ws + (size_t)2 * 33554432);
  unsigned short* Wb = (unsigned short*)(ws + (size_t)3 * 33554432);
  int* flags         = (int*)(ws + (size_t)3 * 33554432 + 6291456);

  prep_x<<<65536, 256, 0, stream>>>(x, Xb);
  prep_w<<<12288, 256, 0, stream>>>(Whh_f, Wih_f, Whh_b, Wih_b, Wb);
  prep_flags<<<1, 64, 0, stream>>>(flags);
  bigru_rec<<<64, NTHR, 0, stream>>>(Xb, Hf, Hb, Wb, bih_f, bhh_f, bih_b, bhh_b,
                                     flags, out);
}